// Round 6
// baseline (596.035 us; speedup 1.0000x reference)
//
#include <hip/hip_runtime.h>

// FourierBlock: per (b, c): rfft(4096) -> keep top-16 |X| bins -> irfft.
//
// Round 9: same fused single-kernel algorithm (load -> FFT -> top-16 ->
// Chebyshev synthesis -> store), but the 4096-point FFT is now FOUR RADIX-8
// passes executed by a 512-thread block over the same 33 KB LDS spectrum.
// Round-5 counters (occupancy 42%, VALUBusy stuck at 35%) showed a
// latency-bound kernel starved of independent instruction streams, with
// occupancy capped by LDS (32 KB spectrum / block). 512 threads per 33 KB
// doubles waves-per-KB: 4 blocks x 8 waves = 32 waves/CU (8/SIMD), and
// radix-8 halves per-thread register data (8 float2) and chain length.
// __launch_bounds__(512, 8) pins VGPR <= 64 (round 5 fit 64 naturally with
// HIGHER register pressure, so no spill expected).

#define SWZ(i) ((i) ^ (((i) >> 4) & 15))

__device__ __forceinline__ int drev8(int x) {
  // reverse the four octal digits of a 12-bit index (involution)
  return ((x & 7) << 9) | ((x & 0x38) << 3) | ((x >> 3) & 0x38) | ((x >> 9) & 7);
}

__device__ __forceinline__ float2 cmulf(float2 a, float c, float s) {
  return make_float2(a.x * c - a.y * s, a.x * s + a.y * c);
}

__device__ __forceinline__ float2 cadd(float2 a, float2 b) { return make_float2(a.x + b.x, a.y + b.y); }
__device__ __forceinline__ float2 csub(float2 a, float2 b) { return make_float2(a.x - b.x, a.y - b.y); }
__device__ __forceinline__ float2 cmulnegi(float2 a) { return make_float2(a.y, -a.x); }      // a * (-i)
__device__ __forceinline__ float2 cmulposi(float2 a) { return make_float2(-a.y, a.x); }      // a * (+i)

// 8-point DFT in registers, natural-order input AND output (DIF split).
// X[r] = sum_k a[k] e^{-2 pi i r k / 8}.
__device__ __forceinline__ void dft8(float2* a) {
  const float R = 0.7071067811865476f;
  float2 t0 = cadd(a[0], a[4]), t1 = cadd(a[1], a[5]);
  float2 t2 = cadd(a[2], a[6]), t3 = cadd(a[3], a[7]);
  float2 u0 = csub(a[0], a[4]);
  float2 d1 = csub(a[1], a[5]);
  float2 u1 = make_float2(R * (d1.x + d1.y), R * (d1.y - d1.x));   // * W8^1
  float2 u2 = cmulnegi(csub(a[2], a[6]));                          // * W8^2
  float2 d3 = csub(a[3], a[7]);
  float2 u3 = make_float2(R * (d3.y - d3.x), R * (-(d3.x + d3.y))); // * W8^3
  // DFT4(t) -> X[0,2,4,6]
  {
    float2 b0 = cadd(t0, t2), b1 = csub(t0, t2);
    float2 b2 = cadd(t1, t3), b3 = csub(t1, t3);
    a[0] = cadd(b0, b2);
    a[2] = cadd(b1, cmulnegi(b3));
    a[4] = csub(b0, b2);
    a[6] = cadd(b1, cmulposi(b3));
  }
  // DFT4(u) -> X[1,3,5,7]
  {
    float2 b0 = cadd(u0, u2), b1 = csub(u0, u2);
    float2 b2 = cadd(u1, u3), b3 = csub(u1, u3);
    a[1] = cadd(b0, b2);
    a[3] = cadd(b1, cmulnegi(b3));
    a[5] = csub(b0, b2);
    a[7] = cadd(b1, cmulposi(b3));
  }
}

// One radix-8 DIF pass. M = current span (twiddle W_M^{j*r}); M=8 -> last
// pass, no twiddle. Twiddle angle j*r/M revolutions: exact fp32 (M pow2,
// j*r < M), already in [0,1) -> feed v_sin/v_cos directly.
template <int STRIDE, int M>
__device__ __forceinline__ void fft_pass8(float2* Zl, int base, int j) {
  float2 v[8];
  #pragma unroll
  for (int p = 0; p < 8; p++) v[p] = Zl[SWZ(base + j + STRIDE * p)];
  dft8(v);
  #pragma unroll
  for (int r = 1; r < 8; r++) {
    if (M > 8) {
      int a = j * r;                                // < M
      float x = (float)a * (1.0f / (float)M);       // revolutions, exact
      float s = -__builtin_amdgcn_sinf(x);          // e^{-2 pi i x}
      float c =  __builtin_amdgcn_cosf(x);
      v[r] = cmulf(v[r], c, s);
    }
  }
  #pragma unroll
  for (int r = 0; r < 8; r++) Zl[SWZ(base + j + STRIDE * r)] = v[r];
}

// ---------------- fused FFT + top-k + synthesis kernel ---------------------

__global__ __launch_bounds__(512, 8) void fourier_fused(
    const float2* __restrict__ X2, float2* __restrict__ O2) {
  __shared__ float2 Z[4096];        // spectrum workspace; reused for partials
  __shared__ float4 CF[32];         // [ch*16+j] = (a, b, cos_step, sin_step)
  __shared__ float  CFf[32];        // bin frequency f

  const int tid = threadIdx.x;
  // XCD-contiguous remap (bijective: 4096 blocks, 8 XCDs, 512 each):
  // XCD k gets original ids [512k, 512k+512) -> 8 whole batches per XCD;
  // sibling channel-pair blocks of a batch are CONSECUTIVE in remapped
  // order, so they start nearly simultaneously on one XCD and share L2
  // lines for the strided reads and partial-line writes.
  const int o = ((blockIdx.x & 7) << 9) + (blockIdx.x >> 3);
  const int b = o >> 6;
  const int q = o & 63;             // channel pair: channels 2q, 2q+1

  // ---- load: x[b, l, 2q..2q+1] is one float2 -> Z (ch0 = re, ch1 = im)
  const float2* src = X2 + (size_t)b * 4096 * 64 + q;
  #pragma unroll
  for (int k = 0; k < 8; k++) {
    int l = tid + 512 * k;
    Z[SWZ(l)] = src[(size_t)l * 64];
  }
  __syncthreads();

  // ---- forward FFT: 4 radix-8 DIF passes; slot p ends holding bin drev8(p)
  fft_pass8<512, 4096>(Z, 0, tid);
  __syncthreads();
  fft_pass8<64, 512>(Z, (tid >> 6) << 9, tid & 63);
  __syncthreads();
  fft_pass8<8, 64>(Z, (tid >> 3) << 6, tid & 7);
  __syncthreads();
  fft_pass8<1, 8>(Z, tid << 3, 0);
  __syncthreads();

  // ---- top-16 selection: wave 0 = channel 2q, wave 1 = channel 2q+1 ----
  const int wv = tid >> 6;
  const int lane = tid & 63;

  if (wv < 2) {
    const int ch = wv;
    int rF = 0; float rA = 0.f, rB = 0.f;   // captured winner (lanes 0..15)
    float m2[32];
    #pragma unroll
    for (int k = 0; k < 32; k++) {
      int f = lane + (k << 6);
      float2 P = Z[SWZ(drev8(f))];
      float2 Q = Z[SWZ(drev8((4096 - f) & 4095))];
      float xr = ch ? (P.y + Q.y) : (P.x + Q.x);
      float xi = ch ? (Q.x - P.x) : (P.y - Q.y);
      m2[k] = xr * xr + xi * xi;   // 4*|X|^2 (uniform scale, ordering only)
    }
    float m2x = -1.f;              // bin f=2048 (Nyquist), lane 0 only
    if (lane == 0) {
      float2 P = Z[SWZ(4)];        // drev8(2048) == 4
      float t = ch ? P.y : P.x;
      m2x = 4.f * t * t;
    }
    for (int r = 0; r < 16; r++) {
      float bv = -1e30f; int bf = 0;
      #pragma unroll
      for (int k = 0; k < 32; k++) {
        int f = lane + (k << 6);
        if (m2[k] > bv) { bv = m2[k]; bf = f; }   // ascending k: ties -> lower f
      }
      if (m2x > bv) { bv = m2x; bf = 2048; }
      #pragma unroll
      for (int off = 32; off; off >>= 1) {
        float ov = __shfl_down(bv, off);
        int   of = __shfl_down(bf, off);
        if (ov > bv || (ov == bv && of < bf)) { bv = ov; bf = of; }
      }
      bf = __shfl(bf, 0);          // broadcast winner bin
      if (lane == r) {             // capture X[bf] in lane r's registers
        rF = bf;
        float2 P = Z[SWZ(drev8(bf))];
        float2 Q = Z[SWZ(drev8((4096 - bf) & 4095))];
        rA = ch ? 0.5f * (P.y + Q.y) : 0.5f * (P.x + Q.x);
        rB = ch ? 0.5f * (Q.x - P.x) : 0.5f * (P.y - Q.y);
      }
      if (bf == 2048) {
        if (lane == 0) m2x = -2.f;
      } else if ((bf & 63) == lane) {
        int kk = bf >> 6;
        #pragma unroll
        for (int k = 0; k < 32; k++) if (k == kk) m2[k] = -2.f;
      }
    }

    // ---- publish coefficients + stride-512 step constants to LDS.
    //      out[l] = sum alpha*cos(2 pi f l/4096) + beta*sin(...), with
    //      alpha = w*Re(X), beta = -w*Im(X), w = 1/N (f=0,2048) else 2/N.
    //      Step angle f*512/4096 = f/8 rev (exact fp32).
    if (lane < 16) {
      const float inv = 2.44140625e-4f;            // 1/4096
      float w = (rF == 0 || rF == 2048) ? inv : 2.f * inv;
      float fv = (float)rF;
      float dx = fv * 0.125f;
      dx -= floorf(dx);
      float cd = __builtin_amdgcn_cosf(dx);
      float sd = __builtin_amdgcn_sinf(dx);
      CF[ch * 16 + lane] = make_float4(w * rA, -w * rB, cd, sd);
      CFf[ch * 16 + lane] = fv;
    }
  }
  __syncthreads();   // spectrum dead; CF/CFf valid; Z reusable as partials

  // ---- synthesis: thread owns samples l = tid + 512k, k = 0..7, 2 ch.
  // Chebyshev: g(l+512) = T g(l) - g(l-512), T = 2 cos(2 pi f/8).
  // x0 = f*tid/4096 rev exact (f*tid <= 2048*511 < 2^20). Per-channel
  // partials go through the dead spectrum LDS (same-thread addresses, no
  // barrier needed) to keep live VGPRs low (48 state regs per channel).
  float* S = (float*)Z;              // 8192 floats = 2 channels x 4096
  const float tf = (float)tid;
  #pragma unroll
  for (int cc = 0; cc < 2; cc++) {
    float u[16], v[16], T[16];
    #pragma unroll
    for (int j = 0; j < 16; j++) {
      float4 cf = CF[cc * 16 + j];
      float f  = CFf[cc * 16 + j];
      float x0 = f * tf * 2.44140625e-4f;
      x0 -= floorf(x0);
      float c0 = __builtin_amdgcn_cosf(x0);
      float s0 = __builtin_amdgcn_sinf(x0);
      float G = fmaf(cf.x, c0, cf.y * s0);    // g(tid)
      float H = fmaf(cf.y, c0, -cf.x * s0);   // b cos - a sin
      u[j] = G;
      v[j] = fmaf(G, cf.z, -H * cf.w);        // g(tid - 512)
      T[j] = cf.z + cf.z;
    }
    #pragma unroll
    for (int k = 0; k < 8; k += 2) {
      float s0a = 0.f, s1a = 0.f;
      #pragma unroll
      for (int j = 0; j < 16; j++) {
        s0a += u[j];
        v[j] = fmaf(T[j], u[j], -v[j]);       // v <- g(l + 512)
      }
      #pragma unroll
      for (int j = 0; j < 16; j++) {
        s1a += v[j];
        u[j] = fmaf(T[j], v[j], -u[j]);       // u <- g(l + 1024)
      }
      S[cc * 4096 + tid + 512 * k]       = s0a;
      S[cc * 4096 + tid + 512 * (k + 1)] = s1a;
    }
  }

  // ---- store: float2 = 2 channels at one sample, mirror of the load ----
  float2* dst = O2 + (size_t)b * 4096 * 64 + q;
  #pragma unroll
  for (int k = 0; k < 8; k++) {
    int l = tid + 512 * k;
    dst[(size_t)l * 64] = make_float2(S[l], S[4096 + l]);
  }
}

extern "C" void kernel_launch(void* const* d_in, const int* in_sizes, int n_in,
                              void* d_out, int out_size, void* d_ws, size_t ws_size,
                              hipStream_t stream) {
  (void)in_sizes; (void)n_in; (void)ws_size; (void)out_size; (void)d_ws;
  const float2* x = (const float2*)d_in[0];
  float2* out = (float2*)d_out;

  fourier_fused<<<dim3(64 * 64), dim3(512), 0, stream>>>(x, out);
}